// Round 20
// baseline (191.160 us; speedup 1.0000x reference)
//
#include <hip/hip_runtime.h>
#include <hip/hip_bf16.h>
#include <math.h>

#define NTRI 69
#define NPAIR 21
#define NB 128
#define BB 4                 // batches per mid block (inner loop)
#define IN_LEN 864
#define MS_LEN 39744
#define EPSV 1e-5f
#define KZ 8                 // K-split factor for the GEMM

typedef short short8 __attribute__((ext_vector_type(8)));
typedef float f32x4 __attribute__((ext_vector_type(4)));
typedef __hip_bfloat16 bf16;

constexpr int MT[6]   = {3456,5760,7488,8064,8064,6912};
constexpr int MSOFF[7]= {0,3456,9216,16704,24768,32832,39744};

constexpr int pair_l1(int p){ int a=0; while ((a+1)*(a+2)/2 <= p) ++a; return a; }
constexpr int pair_l2(int p){ return p - pair_l1(p)*(pair_l1(p)+1)/2; }

// ---- compile-time Clebsch-Gordan ----
constexpr double cfac(int n){ double f=1.0; for(int i=2;i<=n;++i) f*=(double)i; return f; }
constexpr double csqrt_(double x){
  if (x<=0.0) return 0.0;
  double g = x>1.0 ? x : 1.0;
  for (int i=0;i<100;++i) g = 0.5*(g + x/g);
  return g;
}
constexpr double cg_c(int j1,int m1,int j2,int m2,int j,int m){
  if (m1+m2!=m) return 0.0;
  double pref = csqrt_((2.0*j+1.0)*cfac(j+j1-j2)*cfac(j-j1+j2)*cfac(j1+j2-j)/cfac(j1+j2+j+1));
  pref *= csqrt_(cfac(j+m)*cfac(j-m)*cfac(j1-m1)*cfac(j1+m1)*cfac(j2-m2)*cfac(j2+m2));
  int kmin = 0;
  if (-(j-j2+m1) > kmin) kmin = -(j-j2+m1);
  if (-(j-j1-m2) > kmin) kmin = -(j-j1-m2);
  int kmax = j1+j2-j;
  if (j1-m1 < kmax) kmax = j1-m1;
  if (j2+m2 < kmax) kmax = j2+m2;
  double s = 0.0;
  for (int k=kmin;k<=kmax;++k){
    double d = cfac(k)*cfac(j1+j2-j-k)*cfac(j1-m1-k)*cfac(j2+m2-k)*cfac(j-j2+m1+k)*cfac(j-j1-m2+k);
    s += ((k&1)? -1.0:1.0)/d;
  }
  return pref*s;
}

// compile-time for
template<int I> struct Int { static constexpr int v = I; };
template<int B,int E,class F>
__device__ __forceinline__ void cfor(F f){
  if constexpr (B<E){ f(Int<B>{}); cfor<B+1,E>(f); }
}

struct MPar {
  int bb2[NPAIR][6];            // boff[l] + tpos*1152 (row-major k base)
  int gch2[NPAIR][6];           // global middle-channel base per (pair,l)
  unsigned char opair[NPAIR*3];
  unsigned char oseg[NPAIR*3];
};
struct GMeta { int aoff[6], boff[6], K[6], mt[6], w_off[6], ms_off[7], tb[7]; };

// ---- pair-specialized middle body, diagonal-major; BB-batch inner loop ----
template<int P>
__device__ __forceinline__ void pair_body(
    const float2* __restrict__ act,
    bf16* __restrict__ Bm, float* __restrict__ partial,
    const MPar& mp, int ts, int brel0, int b0)
{
  constexpr int L1=pair_l1(P), L2=pair_l2(P);
  constexpr int N1=2*L1+1, N2=2*L2+1;
  constexpr int LMIN=L1-L2;
  constexpr int LMAX=(L1+L2<5)?(L1+L2):5;
  constexpr int NL=LMAX-LMIN+1;
  int t=ts/24, s=ts-24*t;
  const int a1=24*L1*L1+t*N1, a2=24*L2*L2+s*N2;
  float ss[NL];
  cfor<0,NL>([&](auto I){ ss[decltype(I)::v]=0.f; });
  #pragma unroll 1
  for (int bi=0; bi<BB; ++bi){
    const int brel = brel0 + bi;
    const int b = b0 + brel;
    const float2* ab=act+(size_t)b*IN_LEN;
    float f1r[N1],f1i[N1],f2r[N2],f2i[N2];
    cfor<0,N1>([&](auto X){ constexpr int x=decltype(X)::v;
      float2 v=ab[a1+x]; f1r[x]=v.x; f1i[x]=v.y; });
    cfor<0,N2>([&](auto Y){ constexpr int y=decltype(Y)::v;
      float2 v=ab[a2+y]; f2r[y]=v.x; f2i[y]=v.y; });
    cfor<0,N1+N2-1>([&](auto MAI){
      constexpr int mai=decltype(MAI)::v;
      constexpr int ma=mai-(L1+L2);
      constexpr int AMA = ma<0 ? -ma : ma;
      constexpr int LV0 = AMA>LMIN ? AMA : LMIN;
      if constexpr (LV0<=LMAX){
        float fr[LMAX-LV0+1], fi[LMAX-LV0+1];
        cfor<0,LMAX-LV0+1>([&](auto I){ fr[decltype(I)::v]=0.f; fi[decltype(I)::v]=0.f; });
        constexpr int XLO = (mai-(N2-1))>0 ? (mai-(N2-1)) : 0;
        constexpr int XHI = (N1-1)<mai ? (N1-1) : mai;
        cfor<XLO,XHI+1>([&](auto X){
          constexpr int x=decltype(X)::v;
          constexpr int y=mai-x;
          float pr=f1r[x]*f2r[y]-f1i[x]*f2i[y];
          float pi=f1r[x]*f2i[y]+f1i[x]*f2r[y];
          cfor<LV0,LMAX+1>([&](auto LL){
            constexpr int l=decltype(LL)::v;
            constexpr float cv=(float)cg_c(L1,x-L1,L2,y-L2,l,ma);
            if constexpr (cv!=0.f){
              fr[l-LV0] += cv*pr;
              fi[l-LV0] += cv*pi;
            }
          });
        });
        cfor<LV0,LMAX+1>([&](auto LL){
          constexpr int l=decltype(LL)::v;
          constexpr int NM=2*l+1, KL=2*MT[l];
          constexpr int m=ma+l;
          float r=fr[l-LV0], im=fi[l-LV0];
          ss[l-LMIN] += r*r+im*im;
          size_t rowb=(size_t)mp.bb2[P][l]+(size_t)brel*NM*KL+2*ts;
          union { bf16 h[2]; unsigned u; } pk;
          pk.h[0]=__float2bfloat16(r); pk.h[1]=__float2bfloat16(im);
          *reinterpret_cast<unsigned*>(Bm+rowb+(size_t)m*KL)=pk.u;
        });
      }
    });
  }
  int pg = (b0+brel0)/BB;
  cfor<0,NL>([&](auto I){ constexpr int i=decltype(I)::v;
    partial[(size_t)pg*MS_LEN + mp.gch2[P][LMIN+i] + ts] = ss[i]; });
}

__global__ __launch_bounds__(192)
void k_midp(const float2* __restrict__ act,
            bf16* __restrict__ Bm, float* __restrict__ partial, MPar mp, int b0){
  int bx=blockIdx.x;
  int pair = mp.opair[bx], seg = mp.oseg[bx];
  int ts = seg*192 + (int)threadIdx.x;
  int brel0 = (int)blockIdx.y*BB;
  #define CASE(T) case T: pair_body<T>(act,Bm,partial,mp,ts,brel0,b0); break;
  switch(pair){
    CASE(0) CASE(1) CASE(2) CASE(3) CASE(4) CASE(5) CASE(6) CASE(7) CASE(8)
    CASE(9) CASE(10) CASE(11) CASE(12) CASE(13) CASE(14) CASE(15) CASE(16)
    CASE(17) CASE(18) CASE(19) CASE(20)
    default: break;
  }
  #undef CASE
}

// fused: per-channel scale + scaled stacked-real A build (blocked A layout)
// A layout per l: aoff[l] + kb*384 + row*8 + j
__global__ __launch_bounds__(256)
void k_scaleA(const float* __restrict__ partial, const float* __restrict__ mstd,
              const float2* __restrict__ wts, bf16* __restrict__ Am, GMeta gm){
  int c=blockIdx.x*256+threadIdx.x;
  if (c>=MS_LEN) return;
  int l=0;
  #pragma unroll
  for (int i=1;i<6;++i) if (c>=gm.ms_off[i]) l=i;
  float ss=0.f;
  for (int g=0;g<NB/BB;++g) ss += partial[(size_t)g*MS_LEN+c];
  float bstd = sqrtf(ss/(128.f*(float)(2*l+1)));
  float s = 1.f/(0.5f*(mstd[c]+bstd)+EPSV);
  int mt=gm.mt[l];
  int cl=c-gm.ms_off[l];
  bf16* Al=Am+gm.aoff[l];
  const float2* Wl=wts+gm.w_off[l];
  int base = (cl>>2)*384 + 2*(cl&3);   // kb*384 + j
  #pragma unroll 4
  for (int o=0;o<24;++o){
    float2 w=Wl[(size_t)o*mt+cl];
    union { bf16 h[2]; unsigned u; } p0, p1;
    p0.h[0]=__float2bfloat16(w.x*s);  p0.h[1]=__float2bfloat16(-w.y*s);
    p1.h[0]=__float2bfloat16(w.y*s);  p1.h[1]=__float2bfloat16(w.x*s);
    *reinterpret_cast<unsigned*>(Al+base+o*8)      = p0.u;
    *reinterpret_cast<unsigned*>(Al+base+(24+o)*8) = p1.u;
  }
}

// GEMM: B row-major, staged tile-wise through LDS; A blocked (L2-resident).
__global__ __launch_bounds__(256)
void k_gemm2(const bf16* __restrict__ Am, const bf16* __restrict__ Bm,
             float* __restrict__ part, GMeta gm){
  int bid=blockIdx.x, z=blockIdx.y;
  int l=0;
  #pragma unroll
  for (int i=1;i<6;++i) if (bid>=gm.tb[i]) l=i;
  int ntile=bid-gm.tb[l];
  int K=gm.K[l];
  int tid=threadIdx.x, lane=tid&63, w=tid>>6;
  int r=lane&15, kg=lane>>4;
  int nit=K>>7;
  int nz=(nit+KZ-1)/KZ;
  int it0=z*nz, it1=(nit<it0+nz)?nit:(it0+nz);
  f32x4 acc0={0.f,0.f,0.f,0.f}, acc1=acc0, acc2=acc0;
  __shared__ short sB[16][136];       // 16 rows x 128 k-elems (+8 pad)
  __shared__ float red[3072];
  if (it0<it1){
    const bf16* Al=Am+gm.aoff[l];
    const bf16* Bl=Bm+gm.boff[l]+(size_t)(ntile*16)*K;
    int srow = tid>>4, sch = tid&15;  // staging: row, 16B-chunk
    const bf16* src = Bl + (size_t)srow*K + sch*8;
    short* dst = &sB[srow][sch*8];
    short8 stg = *(const short8*)(src + (size_t)it0*128);
    int kb0 = it0*16 + w*4 + kg;
    const short8* pa0=(const short8*)(Al + (size_t)kb0*384 + r*8);
    const short8* pa1=(const short8*)(Al + (size_t)kb0*384 + (16+r)*8);
    const short8* pa2=(const short8*)(Al + (size_t)kb0*384 + (32+r)*8);
    for (int it=it0; it<it1; ++it){
      *(short8*)dst = stg;
      __syncthreads();
      if (it+1<it1) stg = *(const short8*)(src + (size_t)(it+1)*128);
      short8 cb = *(const short8*)(&sB[r][w*32+kg*8]);
      short8 a0=*pa0, a1=*pa1, a2=*pa2;
      pa0+=768; pa1+=768; pa2+=768;   // advance 16 kb = 6144 elems = 768 short8
      acc0=__builtin_amdgcn_mfma_f32_16x16x32_bf16(a0,cb,acc0,0,0,0);
      acc1=__builtin_amdgcn_mfma_f32_16x16x32_bf16(a1,cb,acc1,0,0,0);
      acc2=__builtin_amdgcn_mfma_f32_16x16x32_bf16(a2,cb,acc2,0,0,0);
      __syncthreads();
    }
  }
  #pragma unroll
  for (int reg=0;reg<4;++reg){
    int row0=kg*4+reg;
    red[(w*48+row0)*16+r]     =acc0[reg];
    red[(w*48+16+row0)*16+r]  =acc1[reg];
    red[(w*48+32+row0)*16+r]  =acc2[reg];
  }
  __syncthreads();
  float* po = part + ((size_t)bid*KZ+z)*768;
  for (int e=tid;e<768;e+=256)
    po[e]=red[e]+red[768+e]+red[1536+e]+red[2304+e];
}

__global__ __launch_bounds__(256)
void k_red(const float* __restrict__ part, float* __restrict__ outf,
           GMeta gm, int b0){
  int bid=blockIdx.x;
  int l=0;
  #pragma unroll
  for (int i=1;i<6;++i) if (bid>=gm.tb[i]) l=i;
  int ntile=bid-gm.tb[l];
  int nm=2*l+1;
  const float* po = part + (size_t)bid*KZ*768;
  for (int e=threadIdx.x;e<768;e+=256){
    float sv=0.f;
    #pragma unroll
    for (int zz=0;zz<KZ;++zz) sv += po[zz*768+e];
    int o=e>>4, cc=e&15;
    int n=ntile*16+cc;
    int bb=n/nm, m=n-bb*nm;
    int b=b0+bb;
    int oo=(o<24)?o:(o-24);
    int comp=(o<24)?0:1;
    outf[((size_t)b*IN_LEN + 24*l*l + oo*nm + m)*2 + comp]=sv;
  }
}

extern "C" void kernel_launch(void* const* d_in, const int* in_sizes, int n_in,
                              void* d_out, int out_size, void* d_ws, size_t ws_size,
                              hipStream_t stream) {
  const float2* act  = (const float2*)d_in[0];
  const float2* wts  = (const float2*)d_in[1];
  const float*  mstd = (const float*)d_in[2];
  float* outf = (float*)d_out;
  (void)in_sizes; (void)n_in; (void)out_size;

  GMeta gm; MPar mp;
  for (int l=0;l<6;++l){ gm.mt[l]=MT[l]; gm.K[l]=2*MT[l]; }
  for (int l=0;l<7;++l) gm.ms_off[l]=MSOFF[l];
  for (int l=0;l<6;++l) gm.w_off[l]=24*gm.ms_off[l];
  int atot=0;
  for (int l=0;l<6;++l){ gm.aoff[l]=atot; atot+=48*gm.K[l]; }

  // enumerate triples -> per-(pair,l) tpos
  int tposPL[NPAIR][6];
  {
    int cnt[6]={0,0,0,0,0,0};
    for (int a=0;a<=5;++a)
      for (int b2=0;b2<=a;++b2){
        int pid=a*(a+1)/2+b2;
        for (int l=a-b2; l<=((a+b2<5)?(a+b2):5); ++l)
          tposPL[pid][l]=cnt[l]++;
      }
  }

  // ---- ws layout ----
  size_t ob=0;
  auto alloc=[&](size_t bytes){ size_t o=ob; ob=(ob+bytes+255)&~255ULL; return o; };
  size_t off_partial = alloc((size_t)(NB/BB)*MS_LEN*4);
  size_t off_A       = alloc((size_t)atot*2);
  size_t off_part    = alloc((size_t)288*KZ*768*4);
  size_t off_B       = ob;

  size_t perB=0;
  for (int l=0;l<6;++l) perB += (size_t)(2*l+1)*gm.K[l]*2;
  int nb=16;
  for (int cand : {128,64,32,16})
    if (off_B + (size_t)cand*perB <= ws_size){ nb=cand; break; }

  { int bo=0; for (int l=0;l<6;++l){ gm.boff[l]=bo; bo+=nb*(2*l+1)*gm.K[l]; } }
  gm.tb[0]=0;
  for (int l=0;l<6;++l) gm.tb[l+1]=gm.tb[l]+nb*(2*l+1)/16;

  for (int p=0;p<NPAIR;++p){
    int a=pair_l1(p), b2=pair_l2(p);
    int lmax=(a+b2<5)?(a+b2):5;
    for (int l=0;l<6;++l){ mp.bb2[p][l]=0; mp.gch2[p][l]=0; }
    for (int l=a-b2;l<=lmax;++l){
      mp.bb2[p][l]  = gm.boff[l] + tposPL[p][l]*1152;   // row-major k base
      mp.gch2[p][l] = MSOFF[l] + tposPL[p][l]*576;
    }
  }

  // heavy-first order over pairs (weight ~ N1*N2*NL)
  {
    int ordp[NPAIR];
    for (int i=0;i<NPAIR;++i) ordp[i]=i;
    auto wgt=[&](int p){
      int a=pair_l1(p), b2=pair_l2(p);
      int lmax=(a+b2<5)?(a+b2):5;
      return (2*a+1)*(2*b2+1)*(lmax-(a-b2)+1);
    };
    for (int i=1;i<NPAIR;++i){
      int v=ordp[i], wv=wgt(v), j=i-1;
      while (j>=0 && wgt(ordp[j])<wv){ ordp[j+1]=ordp[j]; --j; }
      ordp[j+1]=v;
    }
    for (int i=0;i<NPAIR;++i)
      for (int sgi=0;sgi<3;++sgi){
        mp.opair[i*3+sgi]=(unsigned char)ordp[i];
        mp.oseg[i*3+sgi]=(unsigned char)sgi;
      }
  }

  uint8_t* wsb=(uint8_t*)d_ws;
  float* partial =(float*)(wsb+off_partial);
  bf16*  Am      =(bf16*)(wsb+off_A);
  float* part    =(float*)(wsb+off_part);
  bf16*  Bm      =(bf16*)(wsb+off_B);

  int tiles=gm.tb[6];
  if (nb==NB){
    k_midp<<<dim3(NPAIR*3,NB/BB),192,0,stream>>>(act,Bm,partial,mp,0);
    k_scaleA<<<(MS_LEN+255)/256,256,0,stream>>>(partial,mstd,wts,Am,gm);
    k_gemm2<<<dim3(tiles,KZ),256,0,stream>>>(Am,Bm,part,gm);
    k_red<<<tiles,256,0,stream>>>(part,outf,gm,0);
  } else {
    for (int b0=0;b0<NB;b0+=nb)
      k_midp<<<dim3(NPAIR*3,nb/BB),192,0,stream>>>(act,Bm,partial,mp,b0);
    k_scaleA<<<(MS_LEN+255)/256,256,0,stream>>>(partial,mstd,wts,Am,gm);
    for (int b0=0;b0<NB;b0+=nb){
      k_midp<<<dim3(NPAIR*3,nb/BB),192,0,stream>>>(act,Bm,partial,mp,b0);
      k_gemm2<<<dim3(tiles,KZ),256,0,stream>>>(Am,Bm,part,gm);
      k_red<<<tiles,256,0,stream>>>(part,outf,gm,b0);
    }
  }
}

// Round 21
// 92.241 us; speedup vs baseline: 2.0724x; 2.0724x over previous
//
#include <hip/hip_runtime.h>
#include <hip/hip_bf16.h>
#include <math.h>

#define NTRI 69
#define NPAIR 21
#define NB 128
#define IN_LEN 864
#define MS_LEN 39744
#define EPSV 1e-5f
#define KZ 8                 // K-split factor for the GEMM

typedef short short8 __attribute__((ext_vector_type(8)));
typedef float f32x4 __attribute__((ext_vector_type(4)));
typedef __hip_bfloat16 bf16;

constexpr int MT[6]   = {3456,5760,7488,8064,8064,6912};
constexpr int MSOFF[7]= {0,3456,9216,16704,24768,32832,39744};

constexpr int pair_l1(int p){ int a=0; while ((a+1)*(a+2)/2 <= p) ++a; return a; }
constexpr int pair_l2(int p){ return p - pair_l1(p)*(pair_l1(p)+1)/2; }

// ---- compile-time Clebsch-Gordan ----
constexpr double cfac(int n){ double f=1.0; for(int i=2;i<=n;++i) f*=(double)i; return f; }
constexpr double csqrt_(double x){
  if (x<=0.0) return 0.0;
  double g = x>1.0 ? x : 1.0;
  for (int i=0;i<100;++i) g = 0.5*(g + x/g);
  return g;
}
constexpr double cg_c(int j1,int m1,int j2,int m2,int j,int m){
  if (m1+m2!=m) return 0.0;
  double pref = csqrt_((2.0*j+1.0)*cfac(j+j1-j2)*cfac(j-j1+j2)*cfac(j1+j2-j)/cfac(j1+j2+j+1));
  pref *= csqrt_(cfac(j+m)*cfac(j-m)*cfac(j1-m1)*cfac(j1+m1)*cfac(j2-m2)*cfac(j2+m2));
  int kmin = 0;
  if (-(j-j2+m1) > kmin) kmin = -(j-j2+m1);
  if (-(j-j1-m2) > kmin) kmin = -(j-j1-m2);
  int kmax = j1+j2-j;
  if (j1-m1 < kmax) kmax = j1-m1;
  if (j2+m2 < kmax) kmax = j2+m2;
  double s = 0.0;
  for (int k=kmin;k<=kmax;++k){
    double d = cfac(k)*cfac(j1+j2-j-k)*cfac(j1-m1-k)*cfac(j2+m2-k)*cfac(j-j2+m1+k)*cfac(j-j1-m2+k);
    s += ((k&1)? -1.0:1.0)/d;
  }
  return pref*s;
}

// compile-time for
template<int I> struct Int { static constexpr int v = I; };
template<int B,int E,class F>
__device__ __forceinline__ void cfor(F f){
  if constexpr (B<E){ f(Int<B>{}); cfor<B+1,E>(f); }
}

struct MPar {
  int bb2[NPAIR][6];            // boff[l] + tpos*1152 (row-major k base)
  int gch2[NPAIR][6];           // global middle-channel base per (pair,l)
  unsigned char opair[NPAIR*3];
  unsigned char oseg[NPAIR*3];
};
struct GMeta { int aoff[6], boff[6], K[6], mt[6], w_off[6], ms_off[7], tb[7]; };

// ---- pair-specialized middle body, diagonal-major; ROW-MAJOR B stores ----
template<int P>
__device__ __forceinline__ void pair_body(
    const float2* __restrict__ act,
    bf16* __restrict__ Bm, float* __restrict__ partial,
    const MPar& mp, int ts, int brel, int b0)
{
  constexpr int L1=pair_l1(P), L2=pair_l2(P);
  constexpr int N1=2*L1+1, N2=2*L2+1;
  constexpr int LMIN=L1-L2;
  constexpr int LMAX=(L1+L2<5)?(L1+L2):5;
  constexpr int NL=LMAX-LMIN+1;
  int t=ts/24, s=ts-24*t;
  const int a1=24*L1*L1+t*N1, a2=24*L2*L2+s*N2;
  const int b=b0+brel;
  const float2* ab=act+(size_t)b*IN_LEN;
  float f1r[N1],f1i[N1],f2r[N2],f2i[N2];
  cfor<0,N1>([&](auto X){ constexpr int x=decltype(X)::v;
    float2 v=ab[a1+x]; f1r[x]=v.x; f1i[x]=v.y; });
  cfor<0,N2>([&](auto Y){ constexpr int y=decltype(Y)::v;
    float2 v=ab[a2+y]; f2r[y]=v.x; f2i[y]=v.y; });
  float ss[NL];
  cfor<0,NL>([&](auto I){ ss[decltype(I)::v]=0.f; });
  cfor<0,N1+N2-1>([&](auto MAI){
    constexpr int mai=decltype(MAI)::v;
    constexpr int ma=mai-(L1+L2);
    constexpr int AMA = ma<0 ? -ma : ma;
    constexpr int LV0 = AMA>LMIN ? AMA : LMIN;
    if constexpr (LV0<=LMAX){
      float fr[LMAX-LV0+1], fi[LMAX-LV0+1];
      cfor<0,LMAX-LV0+1>([&](auto I){ fr[decltype(I)::v]=0.f; fi[decltype(I)::v]=0.f; });
      constexpr int XLO = (mai-(N2-1))>0 ? (mai-(N2-1)) : 0;
      constexpr int XHI = (N1-1)<mai ? (N1-1) : mai;
      cfor<XLO,XHI+1>([&](auto X){
        constexpr int x=decltype(X)::v;
        constexpr int y=mai-x;
        float pr=f1r[x]*f2r[y]-f1i[x]*f2i[y];
        float pi=f1r[x]*f2i[y]+f1i[x]*f2r[y];
        cfor<LV0,LMAX+1>([&](auto LL){
          constexpr int l=decltype(LL)::v;
          constexpr float cv=(float)cg_c(L1,x-L1,L2,y-L2,l,ma);
          if constexpr (cv!=0.f){
            fr[l-LV0] += cv*pr;
            fi[l-LV0] += cv*pi;
          }
        });
      });
      cfor<LV0,LMAX+1>([&](auto LL){
        constexpr int l=decltype(LL)::v;
        constexpr int NM=2*l+1, KL=2*MT[l];
        constexpr int m=ma+l;
        float r=fr[l-LV0], im=fi[l-LV0];
        ss[l-LMIN] += r*r+im*im;
        size_t rowb=(size_t)mp.bb2[P][l]+(size_t)brel*NM*KL+2*ts;
        union { bf16 h[2]; unsigned u; } pk;
        pk.h[0]=__float2bfloat16(r); pk.h[1]=__float2bfloat16(im);
        *reinterpret_cast<unsigned*>(Bm+rowb+(size_t)m*KL)=pk.u;
      });
    }
  });
  cfor<0,NL>([&](auto I){ constexpr int i=decltype(I)::v;
    partial[(size_t)b*MS_LEN + mp.gch2[P][LMIN+i] + ts] = ss[i]; });
}

__global__ __launch_bounds__(192)
void k_midp(const float2* __restrict__ act,
            bf16* __restrict__ Bm, float* __restrict__ partial, MPar mp, int b0){
  int bx=blockIdx.x;
  int pair = mp.opair[bx], seg = mp.oseg[bx];
  int ts = seg*192 + (int)threadIdx.x;
  int brel = (int)blockIdx.y;
  #define CASE(T) case T: pair_body<T>(act,Bm,partial,mp,ts,brel,b0); break;
  switch(pair){
    CASE(0) CASE(1) CASE(2) CASE(3) CASE(4) CASE(5) CASE(6) CASE(7) CASE(8)
    CASE(9) CASE(10) CASE(11) CASE(12) CASE(13) CASE(14) CASE(15) CASE(16)
    CASE(17) CASE(18) CASE(19) CASE(20)
    default: break;
  }
  #undef CASE
}

// fused: per-channel scale + scaled stacked-real A build (blocked A layout)
// A layout per l: aoff[l] + kb*384 + row*8 + j
__global__ __launch_bounds__(256)
void k_scaleA(const float* __restrict__ partial, const float* __restrict__ mstd,
              const float2* __restrict__ wts, bf16* __restrict__ Am, GMeta gm){
  int c=blockIdx.x*256+threadIdx.x;
  if (c>=MS_LEN) return;
  int l=0;
  #pragma unroll
  for (int i=1;i<6;++i) if (c>=gm.ms_off[i]) l=i;
  float ss=0.f;
  for (int g=0;g<NB;++g) ss += partial[(size_t)g*MS_LEN+c];
  float bstd = sqrtf(ss/(128.f*(float)(2*l+1)));
  float s = 1.f/(0.5f*(mstd[c]+bstd)+EPSV);
  int mt=gm.mt[l];
  int cl=c-gm.ms_off[l];
  bf16* Al=Am+gm.aoff[l];
  const float2* Wl=wts+gm.w_off[l];
  int base = (cl>>2)*384 + 2*(cl&3);   // kb*384 + j
  #pragma unroll 4
  for (int o=0;o<24;++o){
    float2 w=Wl[(size_t)o*mt+cl];
    union { bf16 h[2]; unsigned u; } p0, p1;
    p0.h[0]=__float2bfloat16(w.x*s);  p0.h[1]=__float2bfloat16(-w.y*s);
    p1.h[0]=__float2bfloat16(w.y*s);  p1.h[1]=__float2bfloat16(w.x*s);
    *reinterpret_cast<unsigned*>(Al+base+o*8)      = p0.u;
    *reinterpret_cast<unsigned*>(Al+base+(24+o)*8) = p1.u;
  }
}

// GEMM: B row-major, staged tile-wise through LDS; A blocked (L2-resident).
__global__ __launch_bounds__(256)
void k_gemm2(const bf16* __restrict__ Am, const bf16* __restrict__ Bm,
             float* __restrict__ part, GMeta gm){
  int bid=blockIdx.x, z=blockIdx.y;
  int l=0;
  #pragma unroll
  for (int i=1;i<6;++i) if (bid>=gm.tb[i]) l=i;
  int ntile=bid-gm.tb[l];
  int K=gm.K[l];
  int tid=threadIdx.x, lane=tid&63, w=tid>>6;
  int r=lane&15, kg=lane>>4;
  int nit=K>>7;
  int nz=(nit+KZ-1)/KZ;
  int it0=z*nz, it1=(nit<it0+nz)?nit:(it0+nz);
  f32x4 acc0={0.f,0.f,0.f,0.f}, acc1=acc0, acc2=acc0;
  __shared__ short sB[16][136];       // 16 rows x 128 k-elems (+8 pad)
  __shared__ float red[3072];
  if (it0<it1){
    const bf16* Al=Am+gm.aoff[l];
    const bf16* Bl=Bm+gm.boff[l]+(size_t)(ntile*16)*K;
    int srow = tid>>4, sch = tid&15;  // staging: row, 16B-chunk
    const bf16* src = Bl + (size_t)srow*K + sch*8;
    short* dst = &sB[srow][sch*8];
    short8 stg = *(const short8*)(src + (size_t)it0*128);
    int kb0 = it0*16 + w*4 + kg;
    const short8* pa0=(const short8*)(Al + (size_t)kb0*384 + r*8);
    const short8* pa1=(const short8*)(Al + (size_t)kb0*384 + (16+r)*8);
    const short8* pa2=(const short8*)(Al + (size_t)kb0*384 + (32+r)*8);
    for (int it=it0; it<it1; ++it){
      *(short8*)dst = stg;
      __syncthreads();
      if (it+1<it1) stg = *(const short8*)(src + (size_t)(it+1)*128);
      short8 cb = *(const short8*)(&sB[r][w*32+kg*8]);
      short8 a0=*pa0, a1=*pa1, a2=*pa2;
      pa0+=768; pa1+=768; pa2+=768;   // advance 16 kb = 6144 elems = 768 short8
      acc0=__builtin_amdgcn_mfma_f32_16x16x32_bf16(a0,cb,acc0,0,0,0);
      acc1=__builtin_amdgcn_mfma_f32_16x16x32_bf16(a1,cb,acc1,0,0,0);
      acc2=__builtin_amdgcn_mfma_f32_16x16x32_bf16(a2,cb,acc2,0,0,0);
      __syncthreads();
    }
  }
  #pragma unroll
  for (int reg=0;reg<4;++reg){
    int row0=kg*4+reg;
    red[(w*48+row0)*16+r]     =acc0[reg];
    red[(w*48+16+row0)*16+r]  =acc1[reg];
    red[(w*48+32+row0)*16+r]  =acc2[reg];
  }
  __syncthreads();
  float* po = part + ((size_t)bid*KZ+z)*768;
  for (int e=tid;e<768;e+=256)
    po[e]=red[e]+red[768+e]+red[1536+e]+red[2304+e];
}

__global__ __launch_bounds__(256)
void k_red(const float* __restrict__ part, float* __restrict__ outf,
           GMeta gm, int b0){
  int bid=blockIdx.x;
  int l=0;
  #pragma unroll
  for (int i=1;i<6;++i) if (bid>=gm.tb[i]) l=i;
  int ntile=bid-gm.tb[l];
  int nm=2*l+1;
  const float* po = part + (size_t)bid*KZ*768;
  for (int e=threadIdx.x;e<768;e+=256){
    float sv=0.f;
    #pragma unroll
    for (int zz=0;zz<KZ;++zz) sv += po[zz*768+e];
    int o=e>>4, cc=e&15;
    int n=ntile*16+cc;
    int bb=n/nm, m=n-bb*nm;
    int b=b0+bb;
    int oo=(o<24)?o:(o-24);
    int comp=(o<24)?0:1;
    outf[((size_t)b*IN_LEN + 24*l*l + oo*nm + m)*2 + comp]=sv;
  }
}

extern "C" void kernel_launch(void* const* d_in, const int* in_sizes, int n_in,
                              void* d_out, int out_size, void* d_ws, size_t ws_size,
                              hipStream_t stream) {
  const float2* act  = (const float2*)d_in[0];
  const float2* wts  = (const float2*)d_in[1];
  const float*  mstd = (const float*)d_in[2];
  float* outf = (float*)d_out;
  (void)in_sizes; (void)n_in; (void)out_size;

  GMeta gm; MPar mp;
  for (int l=0;l<6;++l){ gm.mt[l]=MT[l]; gm.K[l]=2*MT[l]; }
  for (int l=0;l<7;++l) gm.ms_off[l]=MSOFF[l];
  for (int l=0;l<6;++l) gm.w_off[l]=24*gm.ms_off[l];
  int atot=0;
  for (int l=0;l<6;++l){ gm.aoff[l]=atot; atot+=48*gm.K[l]; }

  // enumerate triples -> per-(pair,l) tpos
  int tposPL[NPAIR][6];
  {
    int cnt[6]={0,0,0,0,0,0};
    for (int a=0;a<=5;++a)
      for (int b2=0;b2<=a;++b2){
        int pid=a*(a+1)/2+b2;
        for (int l=a-b2; l<=((a+b2<5)?(a+b2):5); ++l)
          tposPL[pid][l]=cnt[l]++;
      }
  }

  // ---- ws layout ----
  size_t ob=0;
  auto alloc=[&](size_t bytes){ size_t o=ob; ob=(ob+bytes+255)&~255ULL; return o; };
  size_t off_partial = alloc((size_t)NB*MS_LEN*4);
  size_t off_A       = alloc((size_t)atot*2);
  size_t off_part    = alloc((size_t)288*KZ*768*4);
  size_t off_B       = ob;

  size_t perB=0;
  for (int l=0;l<6;++l) perB += (size_t)(2*l+1)*gm.K[l]*2;
  int nb=16;
  for (int cand : {128,64,32,16})
    if (off_B + (size_t)cand*perB <= ws_size){ nb=cand; break; }

  { int bo=0; for (int l=0;l<6;++l){ gm.boff[l]=bo; bo+=nb*(2*l+1)*gm.K[l]; } }
  gm.tb[0]=0;
  for (int l=0;l<6;++l) gm.tb[l+1]=gm.tb[l]+nb*(2*l+1)/16;

  for (int p=0;p<NPAIR;++p){
    int a=pair_l1(p), b2=pair_l2(p);
    int lmax=(a+b2<5)?(a+b2):5;
    for (int l=0;l<6;++l){ mp.bb2[p][l]=0; mp.gch2[p][l]=0; }
    for (int l=a-b2;l<=lmax;++l){
      mp.bb2[p][l]  = gm.boff[l] + tposPL[p][l]*1152;   // row-major k base
      mp.gch2[p][l] = MSOFF[l] + tposPL[p][l]*576;
    }
  }

  // heavy-first order over pairs (weight ~ N1*N2*NL)
  {
    int ordp[NPAIR];
    for (int i=0;i<NPAIR;++i) ordp[i]=i;
    auto wgt=[&](int p){
      int a=pair_l1(p), b2=pair_l2(p);
      int lmax=(a+b2<5)?(a+b2):5;
      return (2*a+1)*(2*b2+1)*(lmax-(a-b2)+1);
    };
    for (int i=1;i<NPAIR;++i){
      int v=ordp[i], wv=wgt(v), j=i-1;
      while (j>=0 && wgt(ordp[j])<wv){ ordp[j+1]=ordp[j]; --j; }
      ordp[j+1]=v;
    }
    for (int i=0;i<NPAIR;++i)
      for (int sgi=0;sgi<3;++sgi){
        mp.opair[i*3+sgi]=(unsigned char)ordp[i];
        mp.oseg[i*3+sgi]=(unsigned char)sgi;
      }
  }

  uint8_t* wsb=(uint8_t*)d_ws;
  float* partial =(float*)(wsb+off_partial);
  bf16*  Am      =(bf16*)(wsb+off_A);
  float* part    =(float*)(wsb+off_part);
  bf16*  Bm      =(bf16*)(wsb+off_B);

  int tiles=gm.tb[6];
  if (nb==NB){
    k_midp<<<dim3(NPAIR*3,NB),192,0,stream>>>(act,Bm,partial,mp,0);
    k_scaleA<<<(MS_LEN+255)/256,256,0,stream>>>(partial,mstd,wts,Am,gm);
    k_gemm2<<<dim3(tiles,KZ),256,0,stream>>>(Am,Bm,part,gm);
    k_red<<<tiles,256,0,stream>>>(part,outf,gm,0);
  } else {
    for (int b0=0;b0<NB;b0+=nb)
      k_midp<<<dim3(NPAIR*3,nb),192,0,stream>>>(act,Bm,partial,mp,b0);
    k_scaleA<<<(MS_LEN+255)/256,256,0,stream>>>(partial,mstd,wts,Am,gm);
    for (int b0=0;b0<NB;b0+=nb){
      k_midp<<<dim3(NPAIR*3,nb),192,0,stream>>>(act,Bm,partial,mp,b0);
      k_gemm2<<<dim3(tiles,KZ),256,0,stream>>>(Am,Bm,part,gm);
      k_red<<<tiles,256,0,stream>>>(part,outf,gm,b0);
    }
  }
}